// Round 9
// baseline (269.953 us; speedup 1.0000x reference)
//
#include <hip/hip_runtime.h>
#include <hip/hip_fp16.h>

#define N_NODES 8192
#define F_IN    512
#define F_OUT   256
#define LOG2E   1.4426950408889634f

typedef __attribute__((ext_vector_type(8))) _Float16 half8;
typedef __attribute__((ext_vector_type(2))) __fp16   fp16x2;
typedef __attribute__((ext_vector_type(4))) float    f32x4;
typedef __attribute__((ext_vector_type(4))) int      i32x4;

union H8U4 { half8 h; uint4 u; };
union H2U  { fp16x2 h; unsigned u; };

// ---------------------------------------------------------------------------
// k_prep: (a) init emax; (b) pack W into f16 hi/lo B-fragment layout
// (same layout as hpack). hi=f16(w), lo=f16(w-hi): 3-term f16 MFMA emulates
// fp32 GEMM to ~2^-20.
// ---------------------------------------------------------------------------
__global__ __launch_bounds__(256) void k_prep(const float* __restrict__ W,
                                              unsigned short* __restrict__ wph,
                                              unsigned short* __restrict__ wpl,
                                              unsigned* __restrict__ emax_u) {
  const int gid = blockIdx.x * 256 + threadIdx.x;   // 512 blocks -> 131072
  if (gid == 0) *emax_u = 0u;
  const int k = gid >> 8;          // 0..511
  const int c = gid & 255;         // 0..255
  const float w = W[(size_t)k * F_OUT + c];
  const _Float16 hi = (_Float16)w;
  const _Float16 lo = (_Float16)(w - (float)hi);
  const size_t idx =
      (((size_t)(k >> 5) * 16 + (c >> 4)) * 64 + (c & 15) + 16 * ((k >> 3) & 3)) * 8 +
      (k & 7);
  wph[idx] = *(const unsigned short*)&hi;
  wpl[idx] = *(const unsigned short*)&lo;
}

// ---------------------------------------------------------------------------
// k_hb r16: MERGED kernel. Blocks [0,256): the proven r9 split-f16 MFMA
// h-GEMM (epilogue now also writes U=exp2(EJ), V=exp2(0.2*EJ) for k_pv's
// factored-exp softmax). Blocks [256,768): the R4-verified adj->bitmask
// streaming pass (ballot pack, coalesced 256B wave reads). Fusing them in one
// dispatch overlaps the 43us adj stream with the ~10us GEMM compute instead
// of serializing two kernels.
// ---------------------------------------------------------------------------
__global__ __launch_bounds__(512) void k_hb(const float* __restrict__ x,
                                            const uint4* __restrict__ wph4,
                                            const uint4* __restrict__ wpl4,
                                            const float* __restrict__ a,
                                            const int* __restrict__ adj,
                                            unsigned short* __restrict__ hpack,
                                            float* __restrict__ EI,
                                            float* __restrict__ EJ,
                                            float* __restrict__ U,
                                            float* __restrict__ V,
                                            unsigned* __restrict__ emax_u,
                                            unsigned long long* __restrict__ bm) {
  __shared__ float eip[4][32], ejp[4][32], emx[32];
  const int tid  = threadIdx.x;
  const int wid  = tid >> 6, lane = tid & 63;

  if (blockIdx.x >= N_NODES / 32) {
    // ---- badj role (R4-verified byte/bit order) ----
    const int bb = blockIdx.x - N_NODES / 32;
    const int nw = 512 * 8;               // 512 badj blocks x 8 waves
    const int gw = bb * 8 + wid;
    const int nchunk = N_NODES * (N_NODES / 64);
    for (int c0 = gw * 4; c0 < nchunk; c0 += nw * 4) {
      const size_t base = (size_t)c0 * 64 + lane;
      const int v0 = __builtin_nontemporal_load(adj + base);
      const int v1 = __builtin_nontemporal_load(adj + base + 64);
      const int v2 = __builtin_nontemporal_load(adj + base + 128);
      const int v3 = __builtin_nontemporal_load(adj + base + 192);
      const unsigned long long m0 = __ballot(v0 > 0);
      const unsigned long long m1 = __ballot(v1 > 0);
      const unsigned long long m2 = __ballot(v2 > 0);
      const unsigned long long m3 = __ballot(v3 > 0);
      if (lane == 0) {
        uint4 s0, s1;
        s0.x = (unsigned)m0; s0.y = (unsigned)(m0 >> 32);
        s0.z = (unsigned)m1; s0.w = (unsigned)(m1 >> 32);
        s1.x = (unsigned)m2; s1.y = (unsigned)(m2 >> 32);
        s1.z = (unsigned)m3; s1.w = (unsigned)(m3 >> 32);
        *(uint4*)(bm + c0)     = s0;
        *(uint4*)(bm + c0 + 2) = s1;
      }
    }
    return;
  }

  // ---- hgemm role (r9, proven) ----
  const int r0   = blockIdx.x * 32;
  const int mg   = wid >> 2, ng = wid & 3;      // 2 row-groups x 4 col-groups
  const int lo16 = lane & 15, hi4 = lane >> 4;

  const float* xrow = x + (size_t)(r0 + mg * 16 + lo16) * F_IN + hi4 * 8;
  const uint4* whb = wph4 + (size_t)(ng * 4) * 64 + lane;  // + (ks*16+nf)*64
  const uint4* wlb = wpl4 + (size_t)(ng * 4) * 64 + lane;

  f32x4 acc[4] = {};

  float4 xa = *(const float4*)(xrow);
  float4 xb = *(const float4*)(xrow + 4);
  uint4 wh[4], wl[4];
#pragma unroll
  for (int nf = 0; nf < 4; ++nf) {
    wh[nf] = whb[(size_t)nf * 64];
    wl[nf] = wlb[(size_t)nf * 64];
  }

#pragma unroll
  for (int ks = 0; ks < 16; ++ks) {
    H8U4 ah, al;
    const float v[8] = {xa.x, xa.y, xa.z, xa.w, xb.x, xb.y, xb.z, xb.w};
#pragma unroll
    for (int j = 0; j < 8; ++j) {
      const _Float16 h = (_Float16)v[j];
      ah.h[j] = h;
      al.h[j] = (_Float16)(v[j] - (float)h);
    }
    if (ks + 1 < 16) {
      xa = *(const float4*)(xrow + (ks + 1) * 32);
      xb = *(const float4*)(xrow + (ks + 1) * 32 + 4);
    }
#pragma unroll
    for (int nf = 0; nf < 4; ++nf) {
      H8U4 bh, bl;
      bh.u = wh[nf];
      bl.u = wl[nf];
      acc[nf] = __builtin_amdgcn_mfma_f32_16x16x32_f16(ah.h, bh.h, acc[nf], 0, 0, 0);
      acc[nf] = __builtin_amdgcn_mfma_f32_16x16x32_f16(al.h, bh.h, acc[nf], 0, 0, 0);
      acc[nf] = __builtin_amdgcn_mfma_f32_16x16x32_f16(ah.h, bl.h, acc[nf], 0, 0, 0);
    }
    if (ks + 1 < 16) {
#pragma unroll
      for (int nf = 0; nf < 4; ++nf) {
        wh[nf] = whb[(size_t)((ks + 1) * 16 + nf) * 64];
        wl[nf] = wlb[(size_t)((ks + 1) * 16 + nf) * 64];
      }
    }
  }

  float asv[4], adv[4];
#pragma unroll
  for (int nf = 0; nf < 4; ++nf) {
    const int c = ng * 64 + nf * 16 + lo16;
    asv[nf] = a[c];
    adv[nf] = a[F_OUT + c];
  }
#pragma unroll
  for (int q = 0; q < 4; ++q) {
    float s1 = acc[0][q] * asv[0] + acc[1][q] * asv[1] + acc[2][q] * asv[2] +
               acc[3][q] * asv[3];
    float s2 = acc[0][q] * adv[0] + acc[1][q] * adv[1] + acc[2][q] * adv[2] +
               acc[3][q] * adv[3];
#pragma unroll
    for (int o = 1; o < 16; o <<= 1) {
      s1 += __shfl_xor(s1, o);
      s2 += __shfl_xor(s2, o);
    }
    if (lo16 == 0) {
      const int rl = mg * 16 + hi4 * 4 + q;
      eip[ng][rl] = s1;
      ejp[ng][rl] = s2;
    }
  }

#pragma unroll
  for (int nf = 0; nf < 4; ++nf) {
#pragma unroll
    for (int q = 0; q < 4; ++q) {
      const int row = r0 + mg * 16 + hi4 * 4 + q;
      const int col = ng * 64 + nf * 16 + lo16;
      const size_t idx =
          (((size_t)(row >> 5) * 16 + (col >> 4)) * 64 + (col & 15) +
           16 * ((row >> 3) & 3)) * 8 + (row & 7);
      const _Float16 hv = (_Float16)acc[nf][q];
      hpack[idx] = *(const unsigned short*)&hv;
    }
  }

  __syncthreads();
  if (tid < 32) {
    const float s1 = eip[0][tid] + eip[1][tid] + eip[2][tid] + eip[3][tid];
    const float s2 = ejp[0][tid] + ejp[1][tid] + ejp[2][tid] + ejp[3][tid];
    const int row = r0 + tid;
    EI[row] = s1 * LOG2E;
    const float e2 = s2 * LOG2E;
    EJ[row] = e2;
    U[row] = __builtin_amdgcn_exp2f(e2);          // exp2(EJ)
    V[row] = __builtin_amdgcn_exp2f(0.2f * e2);   // exp2(0.2*EJ)
    emx[tid] = e2;
  }
  __syncthreads();
  if (tid == 0) {
    float m = emx[0];
#pragma unroll
    for (int i = 1; i < 32; ++i) m = fmaxf(m, emx[i]);
    unsigned b = __float_as_uint(m);
    unsigned u = (b & 0x80000000u) ? ~b : (b | 0x80000000u);
    atomicMax(emax_u, u);
  }
}

// ---------------------------------------------------------------------------
// k_pv r16: BARRIER-FREE main loop. Exchange-free MFMA (r15) + factored-exp
// P: exp2(max(EJ+A1,.2EJ+A2)) == max(U[j]*c1[i], V[j]*c2[i]) with U,V
// precomputed per-j and c1=exp2(A1),c2=exp2(A2) per-row -> P is 2 mul + max +
// bit-test (no trans-pipe exp), so the 4x per-wave redundancy is cheap.
// Masks come from the global bitmask (one u64 per row per 64-tile, byte
// extract) -> no bml LDS exchange -> NO barrier in the loop; waves run fully
// independent and TLP hides B/mask latency. B loaded in two 4-reg batches
// (k-block 1 issued between A-frag builds) to stay under the VGPR cap.
// ---------------------------------------------------------------------------
__global__ __launch_bounds__(512, 4) void k_pv(const unsigned long long* __restrict__ bm,
                                               const uint4* __restrict__ hp4,
                                               const float* __restrict__ EI,
                                               const float* __restrict__ U,
                                               const float* __restrict__ V,
                                               const unsigned* __restrict__ emax_u,
                                               float* __restrict__ npart,
                                               float* __restrict__ dpart,
                                               int ntiles) {
  __shared__ float ul[2048], vl[2048];          // split's U, V (16 KB)
  __shared__ float c1s[64], c2s[64], den[64];
  const int rowbase = blockIdx.x * 64;
  const int split   = blockIdx.y;
  const int jt0     = split * ntiles;
  const int tid     = threadIdx.x;
  const int wid  = tid >> 6, lane = tid & 63;
  const int lo   = lane & 15, hi = lane >> 4;

  float EMAX;
  {
    const unsigned u = *emax_u;
    EMAX = (u & 0x80000000u) ? __uint_as_float(u & 0x7fffffffu) : __uint_as_float(~u);
  }
  if (tid < 64) {
    const float e  = EI[rowbase + tid];
    const float s  = e + EMAX;
    const float mi = fmaxf(s, 0.2f * s);
    c1s[tid] = __builtin_amdgcn_exp2f(e - mi);
    c2s[tid] = __builtin_amdgcn_exp2f(0.2f * e - mi);
    den[tid] = 0.f;
  }
  const bool uselds = (ntiles <= 32);
  if (uselds) {
    int eidx = jt0 * 64 + tid * 4;
    if (eidx > N_NODES - 4) eidx = N_NODES - 4;
    *(float4*)&ul[tid * 4] = *(const float4*)&U[eidx];
    *(float4*)&vl[tid * 4] = *(const float4*)&V[eidx];
  }
  __syncthreads();   // prologue-only barrier

  // per-wave roles: wave (mg,ng), rows mg*32+{lo,16+lo}, k-slots hi.
  const int mg = wid >> 2, ng = wid & 3;
  const int r0l = mg * 32 + lo, r1l = r0l + 16;
  const float c1r0 = c1s[r0l], c2r0 = c2s[r0l];
  const float c1r1 = c1s[r1l], c2r1 = c2s[r1l];
  const unsigned long long* bm0 =
      bm + (size_t)(rowbase + r0l) * (N_NODES / 64) + jt0;
  const unsigned long long* bm1 =
      bm + (size_t)(rowbase + r1l) * (N_NODES / 64) + jt0;
  const uint4* hb = hp4 + (ng * 4) * 64 + lane;
  const float* ug = U + jt0 * 64;   // fallback path
  const float* vg = V + jt0 * 64;

  f32x4 acc[2][4] = {};
  float dacc0 = 0.f, dacc1 = 0.f;

  unsigned long long m0c = bm0[0], m1c = bm1[0];

  // p = mask ? max(u*c1, v*c2) : 0  (8 values -> one packed A-frag)
  auto mk = [&](const float* uu, const float* vv, unsigned mw, float c1, float c2,
                float& dac) -> uint4 {
    float p[8];
#pragma unroll
    for (int e = 0; e < 8; ++e) {
      const float pm = fmaxf(uu[e] * c1, vv[e] * c2);
      p[e] = ((mw >> e) & 1u) ? pm : 0.f;
    }
    dac += ((p[0] + p[1]) + (p[2] + p[3])) + ((p[4] + p[5]) + (p[6] + p[7]));
    H2U q0, q1, q2, q3;
    q0.h = __builtin_amdgcn_cvt_pkrtz(p[0], p[1]);
    q1.h = __builtin_amdgcn_cvt_pkrtz(p[2], p[3]);
    q2.h = __builtin_amdgcn_cvt_pkrtz(p[4], p[5]);
    q3.h = __builtin_amdgcn_cvt_pkrtz(p[6], p[7]);
    uint4 r = {q0.u, q1.u, q2.u, q3.u};
    return r;
  };

  for (int jt = 0; jt < ntiles; ++jt) {
    const int tb = (jt0 + jt) * 2048;
    // B k-block 0 (latency covered by u/v reads + first A-frag builds).
    uint4 b0[4];
#pragma unroll
    for (int f = 0; f < 4; ++f) b0[f] = hb[tb + f * 64];

    // depth-1 mask prefetch for next tile (stays in flight all iteration).
    unsigned long long m0n = 0, m1n = 0;
    if (jt + 1 < ntiles) { m0n = bm0[jt + 1]; m1n = bm1[jt + 1]; }

    // u/v for j-block 0 (j = hi*8..+8) and j-block 1 (j = 32+hi*8..+8).
    float u0[8], v0[8], u1[8], v1[8];
    if (uselds) {
      *(float4*)&u0[0] = *(const float4*)&ul[jt * 64 + hi * 8];
      *(float4*)&u0[4] = *(const float4*)&ul[jt * 64 + hi * 8 + 4];
      *(float4*)&v0[0] = *(const float4*)&vl[jt * 64 + hi * 8];
      *(float4*)&v0[4] = *(const float4*)&vl[jt * 64 + hi * 8 + 4];
      *(float4*)&u1[0] = *(const float4*)&ul[jt * 64 + 32 + hi * 8];
      *(float4*)&u1[4] = *(const float4*)&ul[jt * 64 + 32 + hi * 8 + 4];
      *(float4*)&v1[0] = *(const float4*)&vl[jt * 64 + 32 + hi * 8];
      *(float4*)&v1[4] = *(const float4*)&vl[jt * 64 + 32 + hi * 8 + 4];
    } else {
      *(float4*)&u0[0] = *(const float4*)&ug[jt * 64 + hi * 8];
      *(float4*)&u0[4] = *(const float4*)&ug[jt * 64 + hi * 8 + 4];
      *(float4*)&v0[0] = *(const float4*)&vg[jt * 64 + hi * 8];
      *(float4*)&v0[4] = *(const float4*)&vg[jt * 64 + hi * 8 + 4];
      *(float4*)&u1[0] = *(const float4*)&ug[jt * 64 + 32 + hi * 8];
      *(float4*)&u1[4] = *(const float4*)&ug[jt * 64 + 32 + hi * 8 + 4];
      *(float4*)&v1[0] = *(const float4*)&vg[jt * 64 + 32 + hi * 8];
      *(float4*)&v1[4] = *(const float4*)&vg[jt * 64 + 32 + hi * 8 + 4];
    }

    // mask bytes: byte hi (j-block 0) and byte 4+hi (j-block 1) of the u64.
    const unsigned mw00 = (unsigned)(m0c >> (hi * 8));
    const unsigned mw01 = (unsigned)(m0c >> (32 + hi * 8));
    const unsigned mw10 = (unsigned)(m1c >> (hi * 8));
    const unsigned mw11 = (unsigned)(m1c >> (32 + hi * 8));

    // A-frags for k-block 0; then issue B k-block 1 loads; then k-block 1
    // A-frags (their VALU covers the b1 latency).
    H8U4 a00, a10, a01, a11;
    a00.u = mk(u0, v0, mw00, c1r0, c2r0, dacc0);
    a10.u = mk(u0, v0, mw10, c1r1, c2r1, dacc1);
    uint4 b1[4];
#pragma unroll
    for (int f = 0; f < 4; ++f) b1[f] = hb[tb + 1024 + f * 64];
    a01.u = mk(u1, v1, mw01, c1r0, c2r0, dacc0);
    a11.u = mk(u1, v1, mw11, c1r1, c2r1, dacc1);

    H8U4 b;
    __builtin_amdgcn_s_setprio(1);
    b.u = b0[0];
    acc[0][0] = __builtin_amdgcn_mfma_f32_16x16x32_f16(a00.h, b.h, acc[0][0], 0, 0, 0);
    acc[1][0] = __builtin_amdgcn_mfma_f32_16x16x32_f16(a10.h, b.h, acc[1][0], 0, 0, 0);
    b.u = b0[1];
    acc[0][1] = __builtin_amdgcn_mfma_f32_16x16x32_f16(a00.h, b.h, acc[0][1], 0, 0, 0);
    acc[1][1] = __builtin_amdgcn_mfma_f32_16x16x32_f16(a10.h, b.h, acc[1][1], 0, 0, 0);
    b.u = b0[2];
    acc[0][2] = __builtin_amdgcn_mfma_f32_16x16x32_f16(a00.h, b.h, acc[0][2], 0, 0, 0);
    acc[1][2] = __builtin_amdgcn_mfma_f32_16x16x32_f16(a10.h, b.h, acc[1][2], 0, 0, 0);
    b.u = b0[3];
    acc[0][3] = __builtin_amdgcn_mfma_f32_16x16x32_f16(a00.h, b.h, acc[0][3], 0, 0, 0);
    acc[1][3] = __builtin_amdgcn_mfma_f32_16x16x32_f16(a10.h, b.h, acc[1][3], 0, 0, 0);
    b.u = b1[0];
    acc[0][0] = __builtin_amdgcn_mfma_f32_16x16x32_f16(a01.h, b.h, acc[0][0], 0, 0, 0);
    acc[1][0] = __builtin_amdgcn_mfma_f32_16x16x32_f16(a11.h, b.h, acc[1][0], 0, 0, 0);
    b.u = b1[1];
    acc[0][1] = __builtin_amdgcn_mfma_f32_16x16x32_f16(a01.h, b.h, acc[0][1], 0, 0, 0);
    acc[1][1] = __builtin_amdgcn_mfma_f32_16x16x32_f16(a11.h, b.h, acc[1][1], 0, 0, 0);
    b.u = b1[2];
    acc[0][2] = __builtin_amdgcn_mfma_f32_16x16x32_f16(a01.h, b.h, acc[0][2], 0, 0, 0);
    acc[1][2] = __builtin_amdgcn_mfma_f32_16x16x32_f16(a11.h, b.h, acc[1][2], 0, 0, 0);
    b.u = b1[3];
    acc[0][3] = __builtin_amdgcn_mfma_f32_16x16x32_f16(a01.h, b.h, acc[0][3], 0, 0, 0);
    acc[1][3] = __builtin_amdgcn_mfma_f32_16x16x32_f16(a11.h, b.h, acc[1][3], 0, 0, 0);
    __builtin_amdgcn_s_setprio(0);

    m0c = m0n; m1c = m1n;   // no barrier: waves fully independent
  }

  // den: ng==0 waves carry exactly one copy of each row's partial sums.
  if (ng == 0) {
    atomicAdd(&den[r0l], dacc0);
    atomicAdd(&den[r1l], dacc1);
  }
  __syncthreads();

  float* npb = npart + (size_t)split * N_NODES * F_OUT;
#pragma unroll
  for (int mi_ = 0; mi_ < 2; ++mi_) {
    const int rb = rowbase + (mg * 2 + mi_) * 16 + hi * 4;
#pragma unroll
    for (int nf = 0; nf < 4; ++nf) {
      const int col = ng * 64 + nf * 16 + lo;
#pragma unroll
      for (int r2 = 0; r2 < 4; ++r2)
        __builtin_nontemporal_store(acc[mi_][nf][r2],
                                    &npb[(size_t)(rb + r2) * F_OUT + col]);
    }
  }
  if (tid < 64)
    __builtin_nontemporal_store(den[tid],
                                &dpart[(size_t)split * N_NODES + rowbase + tid]);
}

// ---------------------------------------------------------------------------
// k_fin: combine splits, divide by denom, ELU, write output.
// ---------------------------------------------------------------------------
__global__ __launch_bounds__(256) void k_fin(const float* __restrict__ npart,
                                             const float* __restrict__ dpart,
                                             float* __restrict__ out,
                                             int nsplit) {
  const int gid = blockIdx.x * 256 + threadIdx.x;
  const int row = gid >> 6;
  const int c4  = (gid & 63) << 2;
  f32x4 s = {0.f, 0.f, 0.f, 0.f};
  float d = 0.f;
  for (int sp = 0; sp < nsplit; ++sp) {
    const f32x4 v = __builtin_nontemporal_load(
        (const f32x4*)(npart + ((size_t)sp * N_NODES + row) * F_OUT + c4));
    s += v;
    d += dpart[(size_t)sp * N_NODES + row];
  }
  const float inv = 1.f / d;
  float o[4] = {s.x * inv, s.y * inv, s.z * inv, s.w * inv};
#pragma unroll
  for (int i = 0; i < 4; ++i) o[i] = (o[i] > 0.f) ? o[i] : expm1f(o[i]);
  float4 ov = {o[0], o[1], o[2], o[3]};
  *(float4*)(out + (size_t)row * F_OUT + c4) = ov;
}

// ---------------------------------------------------------------------------
extern "C" void kernel_launch(void* const* d_in, const int* in_sizes, int n_in,
                              void* d_out, int out_size, void* d_ws, size_t ws_size,
                              hipStream_t stream) {
  const float* x   = (const float*)d_in[0];
  const int*   adj = (const int*)d_in[1];
  const float* W   = (const float*)d_in[2];
  const float* a   = (const float*)d_in[3];
  float* out = (float*)d_out;
  char*  ws  = (char*)d_ws;

  unsigned short* hpack = (unsigned short*)ws;  // 4 MB, B-fragment layout
  size_t off = (size_t)4 * 1024 * 1024;
  float* EI = (float*)(ws + off); off += (size_t)N_NODES * 4;
  float* EJ = (float*)(ws + off); off += (size_t)N_NODES * 4;
  float* U  = (float*)(ws + off); off += (size_t)N_NODES * 4;
  float* V  = (float*)(ws + off); off += (size_t)N_NODES * 4;
  unsigned* emax_u = (unsigned*)(ws + off); off += 256;
  float* dpart = (float*)(ws + off); off += (size_t)8 * N_NODES * 4;
  unsigned short* wph = (unsigned short*)(ws + off); off += (size_t)F_IN * F_OUT * 2;
  unsigned short* wpl = (unsigned short*)(ws + off); off += (size_t)F_IN * F_OUT * 2;
  unsigned long long* bmask = (unsigned long long*)(ws + off);
  off += (size_t)N_NODES * (N_NODES / 8);       // 8 MB bitmask
  float* npart = (float*)(ws + off);

  int nsplit = 4;   // proven best (R6: 8 hurt)
  while (nsplit > 1 && off + (size_t)nsplit * N_NODES * F_OUT * 4 > ws_size) nsplit >>= 1;

  k_prep<<<dim3((F_IN * F_OUT) / 256), dim3(256), 0, stream>>>(W, wph, wpl, emax_u);
  k_hb<<<dim3(N_NODES / 32 + 512), dim3(512), 0, stream>>>(
      x, (const uint4*)wph, (const uint4*)wpl, a, adj, hpack, EI, EJ, U, V, emax_u,
      bmask);
  k_pv<<<dim3(128, nsplit), dim3(512), 0, stream>>>(
      bmask, (const uint4*)hpack, EI, U, V, emax_u, npart, dpart, 128 / nsplit);
  k_fin<<<dim3(N_NODES * 64 / 256), dim3(256), 0, stream>>>(npart, dpart, out, nsplit);
}

// Round 10
// 138.590 us; speedup vs baseline: 1.9478x; 1.9478x over previous
//
#include <hip/hip_runtime.h>
#include <hip/hip_fp16.h>

#define N_NODES 8192
#define F_IN    512
#define F_OUT   256
#define LOG2E   1.4426950408889634f

typedef __attribute__((ext_vector_type(8))) _Float16 half8;
typedef __attribute__((ext_vector_type(2))) __fp16   fp16x2;
typedef __attribute__((ext_vector_type(4))) float    f32x4;
typedef __attribute__((ext_vector_type(4))) int      i32x4;

union H8U4 { half8 h; uint4 u; };
union H2U  { fp16x2 h; unsigned u; };

// ---------------------------------------------------------------------------
// k_prep: (a) init emax; (b) pack W into f16 hi/lo B-fragment layout
// (same layout as hpack). hi=f16(w), lo=f16(w-hi): 3-term f16 MFMA emulates
// fp32 GEMM to ~2^-20.
// ---------------------------------------------------------------------------
__global__ __launch_bounds__(256) void k_prep(const float* __restrict__ W,
                                              unsigned short* __restrict__ wph,
                                              unsigned short* __restrict__ wpl,
                                              unsigned* __restrict__ emax_u) {
  const int gid = blockIdx.x * 256 + threadIdx.x;   // 512 blocks -> 131072
  if (gid == 0) *emax_u = 0u;
  const int k = gid >> 8;          // 0..511
  const int c = gid & 255;         // 0..255
  const float w = W[(size_t)k * F_OUT + c];
  const _Float16 hi = (_Float16)w;
  const _Float16 lo = (_Float16)(w - (float)hi);
  const size_t idx =
      (((size_t)(k >> 5) * 16 + (c >> 4)) * 64 + (c & 15) + 16 * ((k >> 3) & 3)) * 8 +
      (k & 7);
  wph[idx] = *(const unsigned short*)&hi;
  wpl[idx] = *(const unsigned short*)&lo;
}

// ---------------------------------------------------------------------------
// k_hgemm (r9, proven): h = x@W via split-f16 MFMA. Unchanged.
// ---------------------------------------------------------------------------
__global__ __launch_bounds__(512) void k_hgemm(const float* __restrict__ x,
                                               const uint4* __restrict__ wph4,
                                               const uint4* __restrict__ wpl4,
                                               const float* __restrict__ a,
                                               unsigned short* __restrict__ hpack,
                                               float* __restrict__ EI,
                                               float* __restrict__ EJ,
                                               unsigned* __restrict__ emax_u) {
  __shared__ float eip[4][32], ejp[4][32], emx[32];
  const int r0   = blockIdx.x * 32;
  const int tid  = threadIdx.x;
  const int wid  = tid >> 6, lane = tid & 63;
  const int mg   = wid >> 2, ng = wid & 3;      // 2 row-groups x 4 col-groups
  const int lo16 = lane & 15, hi4 = lane >> 4;

  const float* xrow = x + (size_t)(r0 + mg * 16 + lo16) * F_IN + hi4 * 8;
  const uint4* whb = wph4 + (size_t)(ng * 4) * 64 + lane;  // + (ks*16+nf)*64
  const uint4* wlb = wpl4 + (size_t)(ng * 4) * 64 + lane;

  f32x4 acc[4] = {};

  float4 xa = *(const float4*)(xrow);
  float4 xb = *(const float4*)(xrow + 4);
  uint4 wh[4], wl[4];
#pragma unroll
  for (int nf = 0; nf < 4; ++nf) {
    wh[nf] = whb[(size_t)nf * 64];
    wl[nf] = wlb[(size_t)nf * 64];
  }

#pragma unroll
  for (int ks = 0; ks < 16; ++ks) {
    H8U4 ah, al;
    const float v[8] = {xa.x, xa.y, xa.z, xa.w, xb.x, xb.y, xb.z, xb.w};
#pragma unroll
    for (int j = 0; j < 8; ++j) {
      const _Float16 h = (_Float16)v[j];
      ah.h[j] = h;
      al.h[j] = (_Float16)(v[j] - (float)h);
    }
    if (ks + 1 < 16) {
      xa = *(const float4*)(xrow + (ks + 1) * 32);
      xb = *(const float4*)(xrow + (ks + 1) * 32 + 4);
    }
#pragma unroll
    for (int nf = 0; nf < 4; ++nf) {
      H8U4 bh, bl;
      bh.u = wh[nf];
      bl.u = wl[nf];
      acc[nf] = __builtin_amdgcn_mfma_f32_16x16x32_f16(ah.h, bh.h, acc[nf], 0, 0, 0);
      acc[nf] = __builtin_amdgcn_mfma_f32_16x16x32_f16(al.h, bh.h, acc[nf], 0, 0, 0);
      acc[nf] = __builtin_amdgcn_mfma_f32_16x16x32_f16(ah.h, bl.h, acc[nf], 0, 0, 0);
    }
    if (ks + 1 < 16) {
#pragma unroll
      for (int nf = 0; nf < 4; ++nf) {
        wh[nf] = whb[(size_t)((ks + 1) * 16 + nf) * 64];
        wl[nf] = wlb[(size_t)((ks + 1) * 16 + nf) * 64];
      }
    }
  }

  float asv[4], adv[4];
#pragma unroll
  for (int nf = 0; nf < 4; ++nf) {
    const int c = ng * 64 + nf * 16 + lo16;
    asv[nf] = a[c];
    adv[nf] = a[F_OUT + c];
  }
#pragma unroll
  for (int q = 0; q < 4; ++q) {
    float s1 = acc[0][q] * asv[0] + acc[1][q] * asv[1] + acc[2][q] * asv[2] +
               acc[3][q] * asv[3];
    float s2 = acc[0][q] * adv[0] + acc[1][q] * adv[1] + acc[2][q] * adv[2] +
               acc[3][q] * adv[3];
#pragma unroll
    for (int o = 1; o < 16; o <<= 1) {
      s1 += __shfl_xor(s1, o);
      s2 += __shfl_xor(s2, o);
    }
    if (lo16 == 0) {
      const int rl = mg * 16 + hi4 * 4 + q;
      eip[ng][rl] = s1;
      ejp[ng][rl] = s2;
    }
  }

#pragma unroll
  for (int nf = 0; nf < 4; ++nf) {
#pragma unroll
    for (int q = 0; q < 4; ++q) {
      const int row = r0 + mg * 16 + hi4 * 4 + q;
      const int col = ng * 64 + nf * 16 + lo16;
      const size_t idx =
          (((size_t)(row >> 5) * 16 + (col >> 4)) * 64 + (col & 15) +
           16 * ((row >> 3) & 3)) * 8 + (row & 7);
      const _Float16 hv = (_Float16)acc[nf][q];
      hpack[idx] = *(const unsigned short*)&hv;
    }
  }

  __syncthreads();
  if (tid < 32) {
    const float s1 = eip[0][tid] + eip[1][tid] + eip[2][tid] + eip[3][tid];
    const float s2 = ejp[0][tid] + ejp[1][tid] + ejp[2][tid] + ejp[3][tid];
    const int row = r0 + tid;
    EI[row] = s1 * LOG2E;
    const float e2 = s2 * LOG2E;
    EJ[row] = e2;
    emx[tid] = e2;
  }
  __syncthreads();
  if (tid == 0) {
    float m = emx[0];
#pragma unroll
    for (int i = 1; i < 32; ++i) m = fmaxf(m, emx[i]);
    unsigned b = __float_as_uint(m);
    unsigned u = (b & 0x80000000u) ? ~b : (b | 0x80000000u);
    atomicMax(emax_u, u);
  }
}

// ---------------------------------------------------------------------------
// k_pv r17: champion r12 (141.8us) with REGISTER-PRESSURE surgery only.
// Diagnosis: with launch_bounds(512,4) the allocator gives the MFMA acc 64
// AGPR slots, leaving 64 arch VGPRs; r12's live set (8 B-regs x4 + adj
// prefetch + transients) exceeded that -> scratch spills (every k_pv variant
// showed WRITE_SIZE >> npart bytes). Changes vs r12:
//  1. B-fragments in two 4-reg batches: batch0 at tile top (P-phase covers),
//     batch1 issued right after barrier-2 (A ds_reads + 8 MFMAs cover).
//  2. ejlo LDS dropped; 0.2*eh computed inline as FMA (-8 transients, -8KB).
// Everything else byte-identical: 2-barrier pipeline, fused adj->bml mask
// staging, depth-2 NT prefetch, setprio MFMA block, nsplit=4.
// ---------------------------------------------------------------------------
__global__ __launch_bounds__(512, 4) void k_pv(const int* __restrict__ adj,
                                               const uint4* __restrict__ hp4,
                                               const float* __restrict__ EI,
                                               const float* __restrict__ EJ,
                                               const unsigned* __restrict__ emax_u,
                                               float* __restrict__ npart,
                                               float* __restrict__ dpart,
                                               int ntiles) {
  __shared__ __align__(16) uint4 ps4[8 * 64];   // 8 KB P tile (A-fragment layout)
  __shared__ float ejhi[2048];                  // split's EJ
  __shared__ float A1[64], A2[64], den[64];
  __shared__ unsigned char bml[2][512];         // double-buffered mask bytes
  const int rowbase = blockIdx.x * 64;
  const int split   = blockIdx.y;
  const int jt0     = split * ntiles;
  const int tid     = threadIdx.x;
  const int wid  = tid >> 6, lane = tid & 63;
  const int lo   = lane & 15, hi = lane >> 4;

  float EMAX;
  {
    const unsigned u = *emax_u;
    EMAX = (u & 0x80000000u) ? __uint_as_float(u & 0x7fffffffu) : __uint_as_float(~u);
  }
  if (tid < 64) {
    const float e  = EI[rowbase + tid];
    const float s  = e + EMAX;
    const float mi = fmaxf(s, 0.2f * s);
    A1[tid] = e - mi;
    A2[tid] = 0.2f * e - mi;
    den[tid] = 0.f;
  }
  const bool uselds = (ntiles <= 32);
  if (uselds) {
    int eidx = jt0 * 64 + tid * 4;              // clamp guard
    if (eidx > N_NODES - 4) eidx = N_NODES - 4;
    *(float4*)&ejhi[tid * 4] = *(const float4*)&EJ[eidx];
  }

  // ---- adj staging role: thread -> (row = tid>>3, col8 = tid&7) ----
  const int arow = tid >> 3;
  const int* aadj = adj + (size_t)(rowbase + arow) * N_NODES + jt0 * 64 + (tid & 7) * 8;
  {
    const i32x4 v0 = __builtin_nontemporal_load((const i32x4*)(aadj));
    const i32x4 v1 = __builtin_nontemporal_load((const i32x4*)(aadj + 4));
    unsigned by = (v0.x > 0) | ((v0.y > 0) << 1) | ((v0.z > 0) << 2) |
                  ((v0.w > 0) << 3) | ((v1.x > 0) << 4) | ((v1.y > 0) << 5) |
                  ((v1.z > 0) << 6) | ((v1.w > 0) << 7);
    bml[0][tid] = (unsigned char)by;
  }
  i32x4 av0 = {0, 0, 0, 0}, av1 = {0, 0, 0, 0};
  if (ntiles > 1) {
    av0 = __builtin_nontemporal_load((const i32x4*)(aadj + 64));
    av1 = __builtin_nontemporal_load((const i32x4*)(aadj + 68));
  }
  __syncthreads();   // A1/A2, ejhi, bml[0] ready

  // P-writer role: slot wid = ksw*4 + msub.
  const int msub = wid & 3, ksw = wid >> 2;
  const int row_p = msub * 16 + lo;
  const int jloc  = ksw * 32 + hi * 8;
  const float a1r = A1[row_p], a2r = A2[row_p];
  const int  mbidx = row_p * 8 + ksw * 4 + hi;   // byte index in bml
  const float* ejg  = EJ + jt0 * 64 + jloc;
  // MFMA-reader role: wave (mg,ng) owns rows [mg*32,+32) x cols [ng*64,+64).
  const int mg = wid >> 2, ng = wid & 3;
  const uint4* hb = hp4 + (ng * 4) * 64 + lane;

  f32x4 acc[2][4] = {};
  float dacc = 0.f;

  for (int jt = 0; jt < ntiles; ++jt) {
    const int tb = (jt0 + jt) * 2048;  // uint4 offset of this tile's first k-block
    // B batch 0 only (k-block 0): 16 regs, latency covered by the P phase.
    const uint4 b00 = hb[tb + 0 * 1024 + 0 * 64];
    const uint4 b01 = hb[tb + 0 * 1024 + 1 * 64];
    const uint4 b02 = hb[tb + 0 * 1024 + 2 * 64];
    const uint4 b03 = hb[tb + 0 * 1024 + 3 * 64];

    // P compute: 8 values/thread; mask byte from bml (written last iter).
    const unsigned mcur = bml[jt & 1][mbidx];
    float eh[8];
    if (uselds) {
      const float4 h0 = *(const float4*)&ejhi[jt * 64 + jloc];
      const float4 h1 = *(const float4*)&ejhi[jt * 64 + jloc + 4];
      eh[0]=h0.x; eh[1]=h0.y; eh[2]=h0.z; eh[3]=h0.w;
      eh[4]=h1.x; eh[5]=h1.y; eh[6]=h1.z; eh[7]=h1.w;
    } else {
      const float4 e0 = *(const float4*)(ejg + jt * 64);
      const float4 e1 = *(const float4*)(ejg + jt * 64 + 4);
      eh[0]=e0.x; eh[1]=e0.y; eh[2]=e0.z; eh[3]=e0.w;
      eh[4]=e1.x; eh[5]=e1.y; eh[6]=e1.z; eh[7]=e1.w;
    }
    float ph[8];
#pragma unroll
    for (int j = 0; j < 8; ++j) {
      const float s = fmaxf(eh[j] + a1r, fmaf(0.2f, eh[j], a2r));
      const float p = __builtin_amdgcn_exp2f(s);
      ph[j] = (mcur & (1u << j)) ? p : 0.f;
    }
    dacc += ((ph[0] + ph[1]) + (ph[2] + ph[3])) + ((ph[4] + ph[5]) + (ph[6] + ph[7]));
    H2U q0, q1, q2, q3;
    q0.h = __builtin_amdgcn_cvt_pkrtz(ph[0], ph[1]);
    q1.h = __builtin_amdgcn_cvt_pkrtz(ph[2], ph[3]);
    q2.h = __builtin_amdgcn_cvt_pkrtz(ph[4], ph[5]);
    q3.h = __builtin_amdgcn_cvt_pkrtz(ph[6], ph[7]);
    uint4 pk = {q0.u, q1.u, q2.u, q3.u};

    asm volatile("" ::: "memory");
    __builtin_amdgcn_s_barrier();        // all waves done reading ps4 (prev tile)
    asm volatile("" ::: "memory");
    ps4[wid * 64 + lane] = pk;
    // Pack mask bytes for tile jt+1 (regs loaded last window); issue coalesced
    // NT loads for tile jt+2 (full tile of latency cover).
    if (jt + 1 < ntiles) {
      unsigned by = (av0.x > 0) | ((av0.y > 0) << 1) | ((av0.z > 0) << 2) |
                    ((av0.w > 0) << 3) | ((av1.x > 0) << 4) | ((av1.y > 0) << 5) |
                    ((av1.z > 0) << 6) | ((av1.w > 0) << 7);
      bml[(jt + 1) & 1][tid] = (unsigned char)by;
      if (jt + 2 < ntiles) {
        const int* ap = aadj + (jt + 2) * 64;
        av0 = __builtin_nontemporal_load((const i32x4*)ap);
        av1 = __builtin_nontemporal_load((const i32x4*)(ap + 4));
      }
    }
    asm volatile("s_waitcnt lgkmcnt(0)" ::: "memory");  // ps4 + bml writes visible
    __builtin_amdgcn_s_barrier();        // P tile ready
    asm volatile("" ::: "memory");

    // B batch 1 (k-block 1) issued now: covered by A ds_reads + 8 MFMAs + TLP.
    const uint4 b10 = hb[tb + 1 * 1024 + 0 * 64];
    const uint4 b11 = hb[tb + 1 * 1024 + 1 * 64];
    const uint4 b12 = hb[tb + 1 * 1024 + 2 * 64];
    const uint4 b13 = hb[tb + 1 * 1024 + 3 * 64];

    H8U4 a00, a01, a10, a11;
    a00.u = ps4[(0 * 4 + mg * 2 + 0) * 64 + lane];
    a10.u = ps4[(0 * 4 + mg * 2 + 1) * 64 + lane];
    a01.u = ps4[(1 * 4 + mg * 2 + 0) * 64 + lane];
    a11.u = ps4[(1 * 4 + mg * 2 + 1) * 64 + lane];
    H8U4 b;
    __builtin_amdgcn_s_setprio(1);
    b.u = b00;
    acc[0][0] = __builtin_amdgcn_mfma_f32_16x16x32_f16(a00.h, b.h, acc[0][0], 0, 0, 0);
    acc[1][0] = __builtin_amdgcn_mfma_f32_16x16x32_f16(a10.h, b.h, acc[1][0], 0, 0, 0);
    b.u = b01;
    acc[0][1] = __builtin_amdgcn_mfma_f32_16x16x32_f16(a00.h, b.h, acc[0][1], 0, 0, 0);
    acc[1][1] = __builtin_amdgcn_mfma_f32_16x16x32_f16(a10.h, b.h, acc[1][1], 0, 0, 0);
    b.u = b02;
    acc[0][2] = __builtin_amdgcn_mfma_f32_16x16x32_f16(a00.h, b.h, acc[0][2], 0, 0, 0);
    acc[1][2] = __builtin_amdgcn_mfma_f32_16x16x32_f16(a10.h, b.h, acc[1][2], 0, 0, 0);
    b.u = b03;
    acc[0][3] = __builtin_amdgcn_mfma_f32_16x16x32_f16(a00.h, b.h, acc[0][3], 0, 0, 0);
    acc[1][3] = __builtin_amdgcn_mfma_f32_16x16x32_f16(a10.h, b.h, acc[1][3], 0, 0, 0);
    b.u = b10;
    acc[0][0] = __builtin_amdgcn_mfma_f32_16x16x32_f16(a01.h, b.h, acc[0][0], 0, 0, 0);
    acc[1][0] = __builtin_amdgcn_mfma_f32_16x16x32_f16(a11.h, b.h, acc[1][0], 0, 0, 0);
    b.u = b11;
    acc[0][1] = __builtin_amdgcn_mfma_f32_16x16x32_f16(a01.h, b.h, acc[0][1], 0, 0, 0);
    acc[1][1] = __builtin_amdgcn_mfma_f32_16x16x32_f16(a11.h, b.h, acc[1][1], 0, 0, 0);
    b.u = b12;
    acc[0][2] = __builtin_amdgcn_mfma_f32_16x16x32_f16(a01.h, b.h, acc[0][2], 0, 0, 0);
    acc[1][2] = __builtin_amdgcn_mfma_f32_16x16x32_f16(a11.h, b.h, acc[1][2], 0, 0, 0);
    b.u = b13;
    acc[0][3] = __builtin_amdgcn_mfma_f32_16x16x32_f16(a01.h, b.h, acc[0][3], 0, 0, 0);
    acc[1][3] = __builtin_amdgcn_mfma_f32_16x16x32_f16(a11.h, b.h, acc[1][3], 0, 0, 0);
    __builtin_amdgcn_s_setprio(0);
  }

  atomicAdd(&den[row_p], dacc);
  __syncthreads();

  float* npb = npart + (size_t)split * N_NODES * F_OUT;
#pragma unroll
  for (int mi_ = 0; mi_ < 2; ++mi_) {
    const int rb = rowbase + (mg * 2 + mi_) * 16 + hi * 4;
#pragma unroll
    for (int nf = 0; nf < 4; ++nf) {
      const int col = ng * 64 + nf * 16 + lo;
#pragma unroll
      for (int r2 = 0; r2 < 4; ++r2)
        __builtin_nontemporal_store(acc[mi_][nf][r2],
                                    &npb[(size_t)(rb + r2) * F_OUT + col]);
    }
  }
  if (tid < 64)
    __builtin_nontemporal_store(den[tid],
                                &dpart[(size_t)split * N_NODES + rowbase + tid]);
}

// ---------------------------------------------------------------------------
// k_fin: combine splits, divide by denom, ELU, write output.
// ---------------------------------------------------------------------------
__global__ __launch_bounds__(256) void k_fin(const float* __restrict__ npart,
                                             const float* __restrict__ dpart,
                                             float* __restrict__ out,
                                             int nsplit) {
  const int gid = blockIdx.x * 256 + threadIdx.x;
  const int row = gid >> 6;
  const int c4  = (gid & 63) << 2;
  f32x4 s = {0.f, 0.f, 0.f, 0.f};
  float d = 0.f;
  for (int sp = 0; sp < nsplit; ++sp) {
    const f32x4 v = __builtin_nontemporal_load(
        (const f32x4*)(npart + ((size_t)sp * N_NODES + row) * F_OUT + c4));
    s += v;
    d += dpart[(size_t)sp * N_NODES + row];
  }
  const float inv = 1.f / d;
  float o[4] = {s.x * inv, s.y * inv, s.z * inv, s.w * inv};
#pragma unroll
  for (int i = 0; i < 4; ++i) o[i] = (o[i] > 0.f) ? o[i] : expm1f(o[i]);
  float4 ov = {o[0], o[1], o[2], o[3]};
  *(float4*)(out + (size_t)row * F_OUT + c4) = ov;
}

// ---------------------------------------------------------------------------
extern "C" void kernel_launch(void* const* d_in, const int* in_sizes, int n_in,
                              void* d_out, int out_size, void* d_ws, size_t ws_size,
                              hipStream_t stream) {
  const float* x   = (const float*)d_in[0];
  const int*   adj = (const int*)d_in[1];
  const float* W   = (const float*)d_in[2];
  const float* a   = (const float*)d_in[3];
  float* out = (float*)d_out;
  char*  ws  = (char*)d_ws;

  unsigned short* hpack = (unsigned short*)ws;  // 4 MB, B-fragment layout
  size_t off = (size_t)4 * 1024 * 1024;
  float* EI = (float*)(ws + off); off += (size_t)N_NODES * 4;
  float* EJ = (float*)(ws + off); off += (size_t)N_NODES * 4;
  unsigned* emax_u = (unsigned*)(ws + off); off += 256;
  float* dpart = (float*)(ws + off); off += (size_t)8 * N_NODES * 4;
  unsigned short* wph = (unsigned short*)(ws + off); off += (size_t)F_IN * F_OUT * 2;
  unsigned short* wpl = (unsigned short*)(ws + off); off += (size_t)F_IN * F_OUT * 2;
  float* npart = (float*)(ws + off);

  int nsplit = 4;   // proven best (R6: 8 hurt)
  while (nsplit > 1 && off + (size_t)nsplit * N_NODES * F_OUT * 4 > ws_size) nsplit >>= 1;

  k_prep<<<dim3((F_IN * F_OUT) / 256), dim3(256), 0, stream>>>(W, wph, wpl, emax_u);
  k_hgemm<<<dim3(N_NODES / 32), dim3(512), 0, stream>>>(
      x, (const uint4*)wph, (const uint4*)wpl, a, hpack, EI, EJ, emax_u);
  k_pv<<<dim3(128, nsplit), dim3(512), 0, stream>>>(adj, (const uint4*)hpack, EI, EJ,
                                                    emax_u, npart, dpart, 128 / nsplit);
  k_fin<<<dim3(N_NODES * 64 / 256), dim3(256), 0, stream>>>(npart, dpart, out, nsplit);
}